// Round 13
// baseline (57.991 us; speedup 1.0000x reference)
//
#include <hip/hip_runtime.h>
#include <hip/hip_bf16.h>

#define NB 128
#define NN 2048
#define DEG 16
#define EMBD 16
#define NL 4
#define OBSD 6154
#define HID 45
#define NOUT 15
#define LOG2E 1.44269504f
#define NW 16            // waves per block
#define CHW 385          // ceil(OBSD / NW) — i-chunk per wave for fc1

__device__ __forceinline__ float frcp(float v) { return __builtin_amdgcn_rcpf(v); }

__device__ __forceinline__ uint32_t pk_bf16(float a, float b) {
    uint32_t ua = __float_as_uint(a); ua += 0x7fffu + ((ua >> 16) & 1u);
    uint32_t ub = __float_as_uint(b); ub += 0x7fffu + ((ub >> 16) & 1u);
    return (ua >> 16) | (ub & 0xffff0000u);
}
__device__ __forceinline__ float lo_bf(uint32_t u) { return __uint_as_float(u << 16); }
__device__ __forceinline__ float hi_bf(uint32_t u) { return __uint_as_float(u & 0xffff0000u); }

__device__ __forceinline__ void ln4(const float* p, const float* g, const float* bb, float* o) {
    float m = 0.25f * (p[0] + p[1] + p[2] + p[3]);
    float var = 0.f;
#pragma unroll
    for (int j = 0; j < 4; ++j) { float d = p[j] - m; var += d * d; }
    var *= 0.25f;
    float rs = rsqrtf(var + 1e-5f);
#pragma unroll
    for (int j = 0; j < 4; ++j) o[j] = g[j] * (p[j] - m) * rs + bb[j];
}

__device__ __forceinline__ void node_tail(float* hh, const float* msg,
    const float* wo, const float* bol, const float* g1, const float* be1,
    const float* w1, const float* b1l, const float* w2, const float* b2l,
    const float* g2, const float* be2)
{
    float pre[4];
#pragma unroll
    for (int j = 0; j < 4; ++j) {
        float s = bol[j];
#pragma unroll
        for (int i = 0; i < 4; ++i) s += msg[i] * wo[i * 4 + j];
        pre[j] = hh[j] + s;
    }
    float hn[4];
    ln4(pre, g1, be1, hn);
    float mid[8];
#pragma unroll
    for (int j = 0; j < 8; ++j) {
        float s = b1l[j];
#pragma unroll
        for (int i = 0; i < 4; ++i) s += hn[i] * w1[i * 8 + j];
        mid[j] = fmaxf(s, 0.f);
    }
    float pre2[4];
#pragma unroll
    for (int j = 0; j < 4; ++j) {
        float s = b2l[j];
#pragma unroll
        for (int i = 0; i < 8; ++i) s += mid[i] * w2[i * 4 + j];
        pre2[j] = hn[j] + s;
    }
    ln4(pre2, g2, be2, hh);
}

__device__ __forceinline__ uint4 kv_pack(const float* hh,
    const float* wk, const float* bkl, const float* wv, const float* bvl)
{
    float kk[4], vv[4];
#pragma unroll
    for (int j = 0; j < 4; ++j) {
        float sk = bkl[j], sv = bvl[j];
#pragma unroll
        for (int i = 0; i < 4; ++i) {
            sk += hh[i] * wk[i * 4 + j];
            sv += hh[i] * wv[i * 4 + j];
        }
        kk[j] = sk; vv[j] = sv;
    }
    return make_uint4(pk_bf16(kk[0], kk[1]), pk_bf16(kk[2], kk[3]),
                      pk_bf16(vv[0], vv[1]), pk_bf16(vv[2], vv[3]));
}

// gather + tail body for a layer (kv staged in LDS, q2 prescaled)
__device__ __forceinline__ void gather_tail(const uint4* kv, const int* su,
    const float* q2, float* hh, int l,
    const float* Wo, const float* bo, const float* ln1_g, const float* ln1_b,
    const float* W1, const float* b1, const float* W2, const float* b2,
    const float* ln2_g, const float* ln2_b)
{
    float z[4] = {0.f, 0.f, 0.f, 0.f}, wa[4] = {0.f, 0.f, 0.f, 0.f};
#pragma unroll
    for (int eb = 0; eb < 4; ++eb) {
        uint4 t0 = kv[su[eb * 4 + 0]];
        uint4 t1 = kv[su[eb * 4 + 1]];
        uint4 t2 = kv[su[eb * 4 + 2]];
        uint4 t3 = kv[su[eb * 4 + 3]];
        float p;
        p = __builtin_amdgcn_exp2f(q2[0] * lo_bf(t0.x)); z[0] += p; wa[0] += p * lo_bf(t0.z);
        p = __builtin_amdgcn_exp2f(q2[1] * hi_bf(t0.x)); z[1] += p; wa[1] += p * hi_bf(t0.z);
        p = __builtin_amdgcn_exp2f(q2[2] * lo_bf(t0.y)); z[2] += p; wa[2] += p * lo_bf(t0.w);
        p = __builtin_amdgcn_exp2f(q2[3] * hi_bf(t0.y)); z[3] += p; wa[3] += p * hi_bf(t0.w);
        p = __builtin_amdgcn_exp2f(q2[0] * lo_bf(t1.x)); z[0] += p; wa[0] += p * lo_bf(t1.z);
        p = __builtin_amdgcn_exp2f(q2[1] * hi_bf(t1.x)); z[1] += p; wa[1] += p * hi_bf(t1.z);
        p = __builtin_amdgcn_exp2f(q2[2] * lo_bf(t1.y)); z[2] += p; wa[2] += p * lo_bf(t1.w);
        p = __builtin_amdgcn_exp2f(q2[3] * hi_bf(t1.y)); z[3] += p; wa[3] += p * hi_bf(t1.w);
        p = __builtin_amdgcn_exp2f(q2[0] * lo_bf(t2.x)); z[0] += p; wa[0] += p * lo_bf(t2.z);
        p = __builtin_amdgcn_exp2f(q2[1] * hi_bf(t2.x)); z[1] += p; wa[1] += p * hi_bf(t2.z);
        p = __builtin_amdgcn_exp2f(q2[2] * lo_bf(t2.y)); z[2] += p; wa[2] += p * lo_bf(t2.w);
        p = __builtin_amdgcn_exp2f(q2[3] * hi_bf(t2.y)); z[3] += p; wa[3] += p * hi_bf(t2.w);
        p = __builtin_amdgcn_exp2f(q2[0] * lo_bf(t3.x)); z[0] += p; wa[0] += p * lo_bf(t3.z);
        p = __builtin_amdgcn_exp2f(q2[1] * hi_bf(t3.x)); z[1] += p; wa[1] += p * hi_bf(t3.z);
        p = __builtin_amdgcn_exp2f(q2[2] * lo_bf(t3.y)); z[2] += p; wa[2] += p * lo_bf(t3.w);
        p = __builtin_amdgcn_exp2f(q2[3] * hi_bf(t3.y)); z[3] += p; wa[3] += p * hi_bf(t3.w);
    }
    float msg[4];
#pragma unroll
    for (int j = 0; j < 4; ++j) msg[j] = wa[j] * frcp(z[j] + 1e-6f);
    node_tail(hh, msg, Wo + l * 16, bo + l * 4, ln1_g + l * 4, ln1_b + l * 4,
              W1 + l * 32, b1 + l * 8, W2 + l * 32, b2 + l * 4,
              ln2_g + l * 4, ln2_b + l * 4);
}

// ===== single kernel: 1 block per graph. GAT (LDS-resident, cone-pruned) + MLP =====
__global__ __launch_bounds__(1024) void mega_kernel(
    const float* __restrict__ x, const int* __restrict__ src,
    const int* __restrict__ agent_nodes,
    const float* __restrict__ obs,
    const float* __restrict__ We, const float* __restrict__ be,
    const float* __restrict__ Wq, const float* __restrict__ bq,
    const float* __restrict__ Wk, const float* __restrict__ bk,
    const float* __restrict__ Wv, const float* __restrict__ bv,
    const float* __restrict__ Wo, const float* __restrict__ bo,
    const float* __restrict__ ln1_g, const float* __restrict__ ln1_b,
    const float* __restrict__ W1, const float* __restrict__ b1,
    const float* __restrict__ W2, const float* __restrict__ b2,
    const float* __restrict__ ln2_g, const float* __restrict__ ln2_b,
    const float* __restrict__ oW1, const float* __restrict__ ob1,
    const float* __restrict__ oW2, const float* __restrict__ ob2,
    const float* __restrict__ oW3, const float* __restrict__ ob3,
    float* __restrict__ out)
{
    __shared__ uint4  kvbuf[NN];          // 32 KB: kv0 then kv1
    __shared__ float4 h1lds[NN];          // 32 KB
    __shared__ int    conen[289];
    __shared__ float  h2c[289][4];
    __shared__ float  h3buf[17][4];
    __shared__ float  red[NW][HID];       // fc1-obs partials
    __shared__ float  hm1s[HID], hm2s[HID];
    const int b = blockIdx.x;
    const int tid = threadIdx.x;
    const int w = tid >> 6, lane = tid & 63;
    const int ag = agent_nodes[b];

    // ---- issue x loads early (embed consumes them after fc1) ----
    float4 xreg[2][4];
#pragma unroll
    for (int c = 0; c < 2; ++c) {
        const float4* xr = reinterpret_cast<const float4*>(
            x + ((size_t)b * NN + c * 1024 + tid) * EMBD);
#pragma unroll
        for (int t4 = 0; t4 < 4; ++t4) xreg[c][t4] = xr[t4];
    }

    // ---- cone node list ----
    if (tid < 17)  conen[tid] = (tid < 16) ? src[ag * DEG + tid] : ag;
    if (tid < 272) {
        const int i = tid >> 4, e = tid & 15;
        const int ti = (i < 16) ? src[ag * DEG + i] : ag;
        conen[17 + tid] = src[ti * DEG + e];
    }

    // ---- fc1 obs-part: wave w covers i in [w*CHW, ...), lane = output j ----
    {
        const int s0 = w * CHW;
        const int s1 = min(s0 + CHW, OBSD);
        const float* ob = obs + (size_t)b * OBSD;
        float a0 = 0.f, a1 = 0.f, a2 = 0.f, a3 = 0.f;
        if (lane < HID) {
            int i = s0;
            for (; i + 4 <= s1; i += 4) {
                a0 += ob[i + 0] * oW1[(size_t)(i + 4) * HID + lane];
                a1 += ob[i + 1] * oW1[(size_t)(i + 5) * HID + lane];
                a2 += ob[i + 2] * oW1[(size_t)(i + 6) * HID + lane];
                a3 += ob[i + 3] * oW1[(size_t)(i + 7) * HID + lane];
            }
            for (; i < s1; ++i) a0 += ob[i] * oW1[(size_t)(i + 4) * HID + lane];
            red[w][lane] = a0 + a1 + a2 + a3;
        }
    }

    // ---- embed + kv0 -> LDS ----
    float he[2][4];
#pragma unroll
    for (int c = 0; c < 2; ++c) {
        float xv[16];
#pragma unroll
        for (int t4 = 0; t4 < 4; ++t4) {
            float4 t = xreg[c][t4];
            xv[t4 * 4 + 0] = t.x; xv[t4 * 4 + 1] = t.y;
            xv[t4 * 4 + 2] = t.z; xv[t4 * 4 + 3] = t.w;
        }
#pragma unroll
        for (int j = 0; j < 4; ++j) {
            float s = be[j];
#pragma unroll
            for (int i = 0; i < 16; ++i) s += xv[i] * We[i * 4 + j];
            he[c][j] = s;
        }
        kvbuf[c * 1024 + tid] = kv_pack(he[c], Wk, bk, Wv, bv);   // layer-0 weights
    }
    __syncthreads();

    // ---- L0 for both nodes ----
    float h1r[2][4];
#pragma unroll
    for (int u = 0; u < 2; ++u) {
        const int n = u * 1024 + tid;
        float q2[4];
#pragma unroll
        for (int j = 0; j < 4; ++j) {
            float sq = bq[j];
#pragma unroll
            for (int i = 0; i < 4; ++i) sq += he[u][i] * Wq[i * 4 + j];
            q2[j] = sq * LOG2E;
        }
        int su[16];
        const int4* sp = reinterpret_cast<const int4*>(src + n * DEG);
#pragma unroll
        for (int t4 = 0; t4 < 4; ++t4) {
            int4 s4 = sp[t4];
            su[t4 * 4 + 0] = s4.x; su[t4 * 4 + 1] = s4.y;
            su[t4 * 4 + 2] = s4.z; su[t4 * 4 + 3] = s4.w;
        }
        float hh[4] = {he[u][0], he[u][1], he[u][2], he[u][3]};
        gather_tail(kvbuf, su, q2, hh, 0, Wo, bo, ln1_g, ln1_b, W1, b1, W2, b2,
                    ln2_g, ln2_b);
#pragma unroll
        for (int j = 0; j < 4; ++j) h1r[u][j] = hh[j];
    }
    __syncthreads();   // all L0 gathers done -> safe to overwrite kvbuf

    // ---- kv1 overwrites kvbuf; h1 -> LDS ----
    {
        const float* wk1 = Wk + 16; const float* bk1 = bk + 4;
        const float* wv1 = Wv + 16; const float* bv1 = bv + 4;
#pragma unroll
        for (int u = 0; u < 2; ++u) {
            const int n = u * 1024 + tid;
            kvbuf[n] = kv_pack(h1r[u], wk1, bk1, wv1, bv1);
            h1lds[n] = make_float4(h1r[u][0], h1r[u][1], h1r[u][2], h1r[u][3]);
        }
    }
    __syncthreads();

    // ---- L1 tails at 289 cone slots ----
    if (tid < 289) {
        const int node = conen[tid];
        float4 hn4 = h1lds[node];
        float hh[4] = {hn4.x, hn4.y, hn4.z, hn4.w};
        float q2[4];
        {
            const float* wq = Wq + 16; const float* bql = bq + 4;
#pragma unroll
            for (int j = 0; j < 4; ++j) {
                float sq = bql[j];
#pragma unroll
                for (int i = 0; i < 4; ++i) sq += hh[i] * wq[i * 4 + j];
                q2[j] = sq * LOG2E;
            }
        }
        int su2[16];
        const int4* sp = reinterpret_cast<const int4*>(src + node * DEG);
#pragma unroll
        for (int t4 = 0; t4 < 4; ++t4) {
            int4 s4 = sp[t4];
            su2[t4 * 4 + 0] = s4.x; su2[t4 * 4 + 1] = s4.y;
            su2[t4 * 4 + 2] = s4.z; su2[t4 * 4 + 3] = s4.w;
        }
        gather_tail(kvbuf, su2, q2, hh, 1, Wo, bo, ln1_g, ln1_b, W1, b1, W2, b2,
                    ln2_g, ln2_b);
#pragma unroll
        for (int j = 0; j < 4; ++j) h2c[tid][j] = hh[j];
    }
    __syncthreads();

    // ---- L2 tails for the 17 C2 nodes (on-demand f32 k/v) ----
    if (tid < 272) {
        const int i = tid >> 4, e = tid & 15;
        const int l2 = 2;
        float q2[4];
        {
            const float* wq = Wq + l2 * 16; const float* bql = bq + l2 * 4;
#pragma unroll
            for (int j = 0; j < 4; ++j) {
                float sq = bql[j];
#pragma unroll
                for (int k = 0; k < 4; ++k) sq += h2c[i][k] * wq[k * 4 + j];
                q2[j] = sq * LOG2E;
            }
        }
        const float* hnb = h2c[17 + tid];
        float z[4], pv[4];
        {
            const float* wk = Wk + l2 * 16; const float* bkl = bk + l2 * 4;
            const float* wv = Wv + l2 * 16; const float* bvl = bv + l2 * 4;
#pragma unroll
            for (int j = 0; j < 4; ++j) {
                float kh = bkl[j], vh = bvl[j];
#pragma unroll
                for (int k = 0; k < 4; ++k) {
                    kh += hnb[k] * wk[k * 4 + j];
                    vh += hnb[k] * wv[k * 4 + j];
                }
                float p = __builtin_amdgcn_exp2f(q2[j] * kh);
                z[j] = p; pv[j] = p * vh;
            }
        }
#pragma unroll
        for (int m = 1; m <= 8; m <<= 1) {
#pragma unroll
            for (int j = 0; j < 4; ++j) {
                z[j]  += __shfl_xor(z[j], m, 64);
                pv[j] += __shfl_xor(pv[j], m, 64);
            }
        }
        if (e == 0) {
            float msg[4];
#pragma unroll
            for (int j = 0; j < 4; ++j) msg[j] = pv[j] * frcp(z[j] + 1e-6f);
            float hh[4] = {h2c[i][0], h2c[i][1], h2c[i][2], h2c[i][3]};
            node_tail(hh, msg, Wo + l2 * 16, bo + l2 * 4, ln1_g + l2 * 4, ln1_b + l2 * 4,
                      W1 + l2 * 32, b1 + l2 * 8, W2 + l2 * 32, b2 + l2 * 4,
                      ln2_g + l2 * 4, ln2_b + l2 * 4);
#pragma unroll
            for (int j = 0; j < 4; ++j) h3buf[i][j] = hh[j];
        }
    }
    __syncthreads();

    // ---- L3 at the agent (wave 0) + fc1 finish ----
    if (tid < 64) {
        const int e = tid >> 2, hd = tid & 3;
        const int l3 = 3;
        float ha[4] = {h3buf[16][0], h3buf[16][1], h3buf[16][2], h3buf[16][3]};
        float qh;
        {
            const float* wq = Wq + l3 * 16;
            qh = bq[l3 * 4 + hd];
#pragma unroll
            for (int i = 0; i < 4; ++i) qh += ha[i] * wq[i * 4 + hd];
            qh *= LOG2E;
        }
        float kh, vh;
        {
            const float* wk3 = Wk + l3 * 16; const float* wv3 = Wv + l3 * 16;
            kh = bk[l3 * 4 + hd]; vh = bv[l3 * 4 + hd];
#pragma unroll
            for (int i = 0; i < 4; ++i) {
                kh += h3buf[e][i] * wk3[i * 4 + hd];
                vh += h3buf[e][i] * wv3[i * 4 + hd];
            }
        }
        float p = __builtin_amdgcn_exp2f(qh * kh);
        float z = p, wv_s = p * vh;
#pragma unroll
        for (int m = 4; m <= 32; m <<= 1) {
            z    += __shfl_xor(z, m, 64);
            wv_s += __shfl_xor(wv_s, m, 64);
        }
        float msg_h = wv_s * frcp(z + 1e-6f);
        float msg[4];
#pragma unroll
        for (int j = 0; j < 4; ++j) msg[j] = __shfl(msg_h, (tid & ~3) + j, 64);

        float hh[4] = {ha[0], ha[1], ha[2], ha[3]};
        node_tail(hh, msg, Wo + l3 * 16, bo + l3 * 4, ln1_g + l3 * 4, ln1_b + l3 * 4,
                  W1 + l3 * 32, b1 + l3 * 8, W2 + l3 * 32, b2 + l3 * 4,
                  ln2_g + l3 * 4, ln2_b + l3 * 4);

        if (tid < HID) {
            float s = ob1[tid];
#pragma unroll
            for (int ww = 0; ww < NW; ++ww) s += red[ww][tid];
#pragma unroll
            for (int k = 0; k < 4; ++k) s += hh[k] * oW1[k * HID + tid];
            hm1s[tid] = tanhf(s);
        }
    }
    __syncthreads();
    if (tid < HID) {
        float s = ob2[tid];
        for (int k = 0; k < HID; ++k) s += hm1s[k] * oW2[k * HID + tid];
        hm2s[tid] = tanhf(s);
    }
    __syncthreads();
    if (tid < NOUT) {
        float s = ob3[tid];
        for (int k = 0; k < HID; ++k) s += hm2s[k] * oW3[k * NOUT + tid];
        out[(size_t)b * NOUT + tid] = s;
    }
}

extern "C" void kernel_launch(void* const* d_in, const int* in_sizes, int n_in,
                              void* d_out, int out_size, void* d_ws, size_t ws_size,
                              hipStream_t stream) {
    const float* x      = (const float*)d_in[0];
    const float* obs    = (const float*)d_in[1];
    const int*   src    = (const int*)d_in[2];
    /* d_in[3] = dst: structurally repeat(arange(N), DEG) — not needed */
    const int*   agent  = (const int*)d_in[4];
    const float* We     = (const float*)d_in[5];
    const float* be     = (const float*)d_in[6];
    const float* Wq     = (const float*)d_in[7];
    const float* bq     = (const float*)d_in[8];
    const float* Wk     = (const float*)d_in[9];
    const float* bk     = (const float*)d_in[10];
    const float* Wv     = (const float*)d_in[11];
    const float* bv     = (const float*)d_in[12];
    const float* Wo     = (const float*)d_in[13];
    const float* bo     = (const float*)d_in[14];
    const float* ln1_g  = (const float*)d_in[15];
    const float* ln1_b  = (const float*)d_in[16];
    const float* W1     = (const float*)d_in[17];
    const float* b1     = (const float*)d_in[18];
    const float* W2     = (const float*)d_in[19];
    const float* b2     = (const float*)d_in[20];
    const float* ln2_g  = (const float*)d_in[21];
    const float* ln2_b  = (const float*)d_in[22];
    const float* oW1    = (const float*)d_in[23];
    const float* ob1    = (const float*)d_in[24];
    const float* oW2    = (const float*)d_in[25];
    const float* ob2    = (const float*)d_in[26];
    const float* oW3    = (const float*)d_in[27];
    const float* ob3    = (const float*)d_in[28];

    float* out = (float*)d_out;

    mega_kernel<<<NB, 1024, 0, stream>>>(x, src, agent, obs,
        We, be, Wq, bq, Wk, bk, Wv, bv, Wo, bo, ln1_g, ln1_b, W1, b1, W2, b2,
        ln2_g, ln2_b, oW1, ob1, oW2, ob2, oW3, ob3, out);
}